// Round 3
// baseline (352.455 us; speedup 1.0000x reference)
//
#include <hip/hip_runtime.h>
#include <hip/hip_bf16.h>

typedef __bf16 bf16x8 __attribute__((ext_vector_type(8)));
typedef short s16x4 __attribute__((ext_vector_type(4)));
typedef float f32x4 __attribute__((ext_vector_type(4)));
typedef unsigned short u16x8 __attribute__((ext_vector_type(8)));

#define MFMA_K32(a, b, c) __builtin_amdgcn_mfma_f32_16x16x32_bf16(a, b, c, 0, 0, 0)

// 16x16x16 bf16 MFMA; builtin exists only in device pass.
static __device__ __forceinline__ f32x4 mfma_k16(s16x4 a, s16x4 b, f32x4 c) {
#ifdef __HIP_DEVICE_COMPILE__
    return __builtin_amdgcn_mfma_f32_16x16x16bf16_1k(a, b, c, 0, 0, 0);
#else
    return c;
#endif
}

static __device__ __forceinline__ float fast_exp2(float x) {
#ifdef __HIP_DEVICE_COMPILE__
    return __builtin_amdgcn_exp2f(x);
#else
    return x;
#endif
}

static __device__ __forceinline__ void prio_hi() {
#ifdef __HIP_DEVICE_COMPILE__
    __builtin_amdgcn_s_setprio(1);
#endif
}
static __device__ __forceinline__ void prio_lo() {
#ifdef __HIP_DEVICE_COMPILE__
    __builtin_amdgcn_s_setprio(0);
#endif
}

// async global->LDS, 16B per lane; lds dest = wave-uniform base + lane*16
#define GLL16(gp, lp)                                              \
    __builtin_amdgcn_global_load_lds(                              \
        (const __attribute__((address_space(1))) void*)(gp),       \
        (__attribute__((address_space(3))) void*)(lp), 16, 0, 0)

// round-to-nearest-even fp32 -> bf16 (finite inputs only)
static __device__ __forceinline__ unsigned short f2bf(float f) {
    unsigned int u = __float_as_uint(f);
    u += 0x7fffu + ((u >> 16) & 1u);
    return (unsigned short)(u >> 16);
}

// packed fp32x2 -> bf16x2 (RNE) via gfx950 v_cvt_pk_bf16_f32 when available
static __device__ __forceinline__ unsigned int cvtpk_bf16(float lo, float hi) {
#if defined(__HIP_DEVICE_COMPILE__) && __has_builtin(__builtin_amdgcn_cvt_pk_bf16_f32)
    typedef __bf16 bf16x2 __attribute__((ext_vector_type(2)));
    bf16x2 r = __builtin_amdgcn_cvt_pk_bf16_f32(lo, hi);
    return __builtin_bit_cast(unsigned int, r);
#else
    return (unsigned int)f2bf(lo) | ((unsigned int)f2bf(hi) << 16);
#endif
}

#define LOG2E 1.44269504088896340736f

// ---------------------------------------------------------------------------
// Fused prep: transpose+cast w_qkv and w_out, rmsnorm x -> xn (bf16).
// bid < 3072: w_qkv tile; < 4096: w_out tile; else rmsnorm row (bid-4096).
// ---------------------------------------------------------------------------
__global__ __launch_bounds__(256) void prep_k(
    const float* __restrict__ x, const float* __restrict__ gamma,
    const float* __restrict__ w_qkv, const float* __restrict__ w_out,
    unsigned short* __restrict__ xn, unsigned short* __restrict__ wtq,
    unsigned short* __restrict__ wto) {
    __shared__ float sm[32][33];
    int bid = blockIdx.x, tid = threadIdx.x;
    if (bid < 4096) {  // transpose paths (block-uniform branch)
        const float* in;
        unsigned short* out;
        int R = 1024, C, bx, by;
        if (bid < 3072) { in = w_qkv; out = wtq; C = 3072; bx = bid % 96; by = bid / 96; }
        else { int b2 = bid - 3072; in = w_out; out = wto; C = 1024; bx = b2 % 32; by = b2 / 32; }
        int c0 = bx * 32, r0 = by * 32;
        int tr = tid >> 5, tc = tid & 31;
#pragma unroll
        for (int i = 0; i < 4; i++)
            sm[tr + i * 8][tc] = in[(size_t)(r0 + tr + i * 8) * C + c0 + tc];
        __syncthreads();
#pragma unroll
        for (int i = 0; i < 4; i++)
            out[(size_t)(c0 + tr + i * 8) * R + r0 + tc] = f2bf(sm[tc][tr + i * 8]);
    } else {  // rmsnorm
        int row = bid - 4096;
        const float* xr = x + (size_t)row * 1024;
        float4 v = *(const float4*)(xr + tid * 4);
        float ss = v.x * v.x + v.y * v.y + v.z * v.z + v.w * v.w;
#pragma unroll
        for (int off = 1; off < 64; off <<= 1) ss += __shfl_xor(ss, off, 64);
        if ((tid & 63) == 0) sm[0][tid >> 6] = ss;
        __syncthreads();
        float tot = sm[0][0] + sm[0][1] + sm[0][2] + sm[0][3];
        float f = 32.0f / fmaxf(sqrtf(tot), 1e-12f);  // sqrt(1024)=32
        float4 g = *(const float4*)(gamma + tid * 4);
        uint2 o;
        o.x = cvtpk_bf16(v.x * f * g.x, v.y * f * g.y);
        o.y = cvtpk_bf16(v.z * f * g.z, v.w * f * g.w);
        *(uint2*)(xn + (size_t)row * 1024 + tid * 4) = o;
    }
}

// ---------------------------------------------------------------------------
// GEMM (m97 structure): C[M,N] = A[M,K] * BT[N,K]^T, bf16 in, fp32 acc.
// BM x 128 tile, BK=32, global_load_lds width-16 staging into unpadded LDS.
// BM=128: 4 waves 2x2 (4x4 frags). BM=64: 4 waves 1x4 (4x2 frags).
// MODE 0: fp32 store. MODE 1: qkv epilogue (q * scale*log2e for exp2-domain
// softmax; k in [bh][n][d]; v transposed to [bh][d][n]).
// ---------------------------------------------------------------------------
template <int MODE, int BM>
__global__ __launch_bounds__(256) void gemm_bt_k(
    const unsigned short* __restrict__ A, const unsigned short* __restrict__ BT,
    float* __restrict__ C, unsigned short* __restrict__ qw,
    unsigned short* __restrict__ kw, unsigned short* __restrict__ vw,
    int M, int N, int K) {
    constexpr int RT = 4;
    constexpr int CT = (BM == 128) ? 4 : 2;
    __shared__ unsigned short As[BM][32];
    __shared__ unsigned short Bs[128][32];
    int tid = threadIdx.x;
    int wave = tid >> 6, lane = tid & 63, quad = lane >> 4, l16 = lane & 15;
    int wrb, wcb;
    if constexpr (BM == 128) { wrb = (wave >> 1) * 64; wcb = (wave & 1) * 64; }
    else { wrb = 0; wcb = wave * 32; }
    int m0 = blockIdx.y * BM, n0 = blockIdx.x * 128;
    int lrow = lane >> 2, lcol = (lane & 3) * 8;  // lane -> (row,col) in 16x32 chunk
    const unsigned short *Ag0, *Ag1 = nullptr;
    if constexpr (BM == 128) {
        Ag0 = A + (size_t)(m0 + wave * 32 + lrow) * K + lcol;
        Ag1 = A + (size_t)(m0 + wave * 32 + 16 + lrow) * K + lcol;
    } else {
        Ag0 = A + (size_t)(m0 + wave * 16 + lrow) * K + lcol;
    }
    const unsigned short* Bg0 = BT + (size_t)(n0 + wave * 32 + lrow) * K + lcol;
    const unsigned short* Bg1 = BT + (size_t)(n0 + wave * 32 + 16 + lrow) * K + lcol;
    f32x4 acc[RT][CT] = {};
    for (int k0 = 0; k0 < K; k0 += 32) {
        __syncthreads();  // prior ds_reads done before overwrite
        if constexpr (BM == 128) {
            GLL16(Ag0 + k0, &As[wave * 32][0]);
            GLL16(Ag1 + k0, &As[wave * 32 + 16][0]);
        } else {
            GLL16(Ag0 + k0, &As[wave * 16][0]);
        }
        GLL16(Bg0 + k0, &Bs[wave * 32][0]);
        GLL16(Bg1 + k0, &Bs[wave * 32 + 16][0]);
        __syncthreads();  // drains vmcnt: staging complete
        bf16x8 af[RT], bfr[CT];
#pragma unroll
        for (int t = 0; t < RT; t++)
            af[t] = *(const bf16x8*)&As[wrb + t * 16 + l16][quad * 8];
#pragma unroll
        for (int t = 0; t < CT; t++)
            bfr[t] = *(const bf16x8*)&Bs[wcb + t * 16 + l16][quad * 8];
#pragma unroll
        for (int rt = 0; rt < RT; rt++)
#pragma unroll
            for (int ct = 0; ct < CT; ct++)
                acc[rt][ct] = MFMA_K32(af[rt], bfr[ct], acc[rt][ct]);
    }
#pragma unroll
    for (int rt = 0; rt < RT; rt++) {
        int mb = m0 + wrb + rt * 16 + quad * 4;
        int b = mb >> 11, nn = mb & 2047;
#pragma unroll
        for (int ct = 0; ct < CT; ct++) {
            int col = n0 + wcb + ct * 16 + l16;
            if (MODE == 0) {
#pragma unroll
                for (int r = 0; r < 4; r++)
                    C[(size_t)(mb + r) * N + col] = acc[rt][ct][r];
            } else {
                int sec = col >> 10, ci = col & 1023;
                int hh = ci >> 6, dd = ci & 63;
                int bh = b * 16 + hh;
                if (sec == 0) {
#pragma unroll
                    for (int r = 0; r < 4; r++)
                        qw[((size_t)bh * 2048 + nn + r) * 64 + dd] =
                            f2bf(acc[rt][ct][r] * (0.125f * LOG2E));
                } else if (sec == 1) {
#pragma unroll
                    for (int r = 0; r < 4; r++)
                        kw[((size_t)bh * 2048 + nn + r) * 64 + dd] = f2bf(acc[rt][ct][r]);
                } else {
                    uint2 pk;
                    pk.x = cvtpk_bf16(acc[rt][ct][0], acc[rt][ct][1]);
                    pk.y = cvtpk_bf16(acc[rt][ct][2], acc[rt][ct][3]);
                    *(uint2*)&vw[((size_t)bh * 64 + dd) * 2048 + nn] = pk;
                }
            }
        }
    }
}

// ---------------------------------------------------------------------------
// Causal flash attention, barrier-free independent waves (round 3).
// R2 post-mortem: occupancy 25->50% bought only 55->53 us. The gate is the
// per-tile serial machinery (block barrier every tile, LDS staging + dbuf,
// 7.6M bank-conflict cycles ~ 12us), all scaling with tile count.
// At D=64 the MFMA A-fragment layouts match global layouts exactly:
//   K  [bh][key][64]: A-frag = 16B contiguous at (key=l16, d=quad*8)  ✓
//   Vt [bh][d][2048]:  A-frag = 8B contiguous at (d=l16, key=quad*4)  ✓
// -> load fragments straight from global (K/V L2-resident: 2MB/XCD set),
// no LDS, no barriers, no staging, no merge. One wave = 16 q-rows x all
// keys, KVBLK=32. 4096 independent waves; adjacent strips share a block so
// L1 catches the common K/V prefix. Sum-reduce shuffles deferred to the
// epilogue (per-lane lrun); only the 2 max-shuffles per tile remain (PV
// needs quad-consistent m). Wave-uniform masked tail tile (t==nfull).
// T13 defer-max with the lrun*=al fix (R1/R2 dropped it - data-dependent
// correctness hole). T5 setprio around MFMA (m191: helps independent-wave
// attn). Heavy-first strip order (LPT).
// ---------------------------------------------------------------------------
__global__ __launch_bounds__(256, 4) void attn_k(
    const unsigned short* __restrict__ q, const unsigned short* __restrict__ k,
    const unsigned short* __restrict__ vt, unsigned short* __restrict__ o) {
    typedef unsigned short ush;
    int bh = blockIdx.x;             // 0..31; XCD = bh%8 -> 2MB K/V set per XCD
    int sg = 31 - (int)blockIdx.y;   // strip group, heavy-first LPT
    int tid = threadIdx.x, wave = tid >> 6, lane = tid & 63;
    int quad = lane >> 4, l16 = lane & 15;
    int s = sg * 4 + wave;           // strip 0..127 (16 q-rows each)
    int q0 = s * 16;
    int b = bh >> 4, h = bh & 15;
    const ush* qg = q + (size_t)bh * 2048 * 64;
    const ush* kg = k + (size_t)bh * 2048 * 64;
    const ush* vg = vt + (size_t)bh * 64 * 2048;

    // Q^T B-operand (held in regs): [k=d=ks*32+quad*8+j][n=qrow=l16]
    bf16x8 bq[2];
#pragma unroll
    for (int ks = 0; ks < 2; ks++)
        bq[ks] = *(const bf16x8*)&qg[(size_t)(q0 + l16) * 64 + ks * 32 + quad * 8];

    f32x4 ot[4] = {};                 // Ot C-layout: [d=dt*16+quad*4+r][qrow=l16]
    float mrun = -1e30f, lrun = 0.f;  // lrun is PER-LANE partial (reduced at end)
    int nfull = q0 >> 5;              // full 32-key tiles; tile nfull is masked

    const ush* kb = kg + (size_t)l16 * 64 + quad * 8;    // K frag base
    const ush* vb = vg + (size_t)l16 * 2048 + quad * 4;  // V frag base

    for (int t = 0; t <= nfull; t++) {
        // fragment loads straight from global (L1/L2-resident)
        const ush* kt_p = kb + (size_t)t * 32 * 64;
        bf16x8 kf0a = *(const bf16x8*)(kt_p);
        bf16x8 kf0b = *(const bf16x8*)(kt_p + 32);
        bf16x8 kf1a = *(const bf16x8*)(kt_p + 16 * 64);
        bf16x8 kf1b = *(const bf16x8*)(kt_p + 16 * 64 + 32);
        s16x4 vf[4][2];
#pragma unroll
        for (int dt = 0; dt < 4; dt++)
#pragma unroll
            for (int ct = 0; ct < 2; ct++)
                vf[dt][ct] = *(const s16x4*)(vb + (size_t)dt * 16 * 2048 + t * 32 + ct * 16);
        // St[key=ct*16+quad*4+r][qrow=l16] = K . Q^T
        f32x4 sf[2];
        prio_hi();
        {
            f32x4 s0 = {};
            s0 = MFMA_K32(kf0a, bq[0], s0);
            s0 = MFMA_K32(kf0b, bq[1], s0);
            sf[0] = s0;
            f32x4 s1 = {};
            s1 = MFMA_K32(kf1a, bq[0], s1);
            s1 = MFMA_K32(kf1b, bq[1], s1);
            sf[1] = s1;
        }
        prio_lo();
        if (t == nfull) {  // tail tile: causal mask (wave-uniform branch)
            int qrow = q0 + l16;
#pragma unroll
            for (int ct = 0; ct < 2; ct++)
#pragma unroll
                for (int r = 0; r < 4; r++)
                    if (t * 32 + ct * 16 + quad * 4 + r > qrow) sf[ct][r] = -1e30f;
        }
        // online softmax (exp2 domain; log2e pre-folded into q)
        float m0 = fmaxf(fmaxf(sf[0][0], sf[0][1]), fmaxf(sf[0][2], sf[0][3]));
        float m1 = fmaxf(fmaxf(sf[1][0], sf[1][1]), fmaxf(sf[1][2], sf[1][3]));
        float mx = fmaxf(m0, m1);
        mx = fmaxf(mx, __shfl_xor(mx, 16, 64));
        mx = fmaxf(mx, __shfl_xor(mx, 32, 64));
        // T13 defer-max: rescale only when max really grew (P <= 2^8 safe)
        if (mx > mrun + 8.0f) {
            float al = fast_exp2(mrun - mx);
            mrun = mx;
            lrun *= al;  // R1/R2 missed this — required for correct normalization
#pragma unroll
            for (int dt = 0; dt < 4; dt++)
#pragma unroll
                for (int r = 0; r < 4; r++) ot[dt][r] *= al;
        }
        float rs = 0.f;
#pragma unroll
        for (int ct = 0; ct < 2; ct++)
#pragma unroll
            for (int r = 0; r < 4; r++) {
                float p = fast_exp2(sf[ct][r] - mrun);
                sf[ct][r] = p;
                rs += p;
            }
        lrun += rs;  // per-lane partial; cross-quad reduce deferred to epilogue
        // P -> packed bf16 B-fragments for 16x16x16 (k=quad*4+j = C-layout)
        s16x4 bpr[2];
#pragma unroll
        for (int ct = 0; ct < 2; ct++) {
            uint2 u;
            u.x = cvtpk_bf16(sf[ct][0], sf[ct][1]);
            u.y = cvtpk_bf16(sf[ct][2], sf[ct][3]);
            bpr[ct] = __builtin_bit_cast(s16x4, u);
        }
        // Ot += V^T * P^T
        prio_hi();
#pragma unroll
        for (int dt = 0; dt < 4; dt++)
#pragma unroll
            for (int ct = 0; ct < 2; ct++)
                ot[dt] = mfma_k16(vf[dt][ct], bpr[ct], ot[dt]);
        prio_lo();
    }
    // epilogue: reduce per-lane lrun across quads (the deferred sum-shuffles)
    lrun += __shfl_xor(lrun, 16, 64);
    lrun += __shfl_xor(lrun, 32, 64);
    float inv = 1.0f / lrun;
    size_t rowbase = ((size_t)b * 2048 + q0 + l16) * 1024 + h * 64;
#pragma unroll
    for (int dt = 0; dt < 4; dt++) {
        uint2 pk;
        pk.x = cvtpk_bf16(ot[dt][0] * inv, ot[dt][1] * inv);
        pk.y = cvtpk_bf16(ot[dt][2] * inv, ot[dt][3] * inv);
        *(uint2*)&o[rowbase + dt * 16 + quad * 4] = pk;
    }
}

extern "C" void kernel_launch(void* const* d_in, const int* in_sizes, int n_in,
                              void* d_out, int out_size, void* d_ws, size_t ws_size,
                              hipStream_t stream) {
    const float* x = (const float*)d_in[0];       // [2,2048,1024]
    const float* gamma = (const float*)d_in[1];   // [1024]
    const float* w_qkv = (const float*)d_in[2];   // [1024,3072]
    const float* w_out = (const float*)d_in[3];   // [1024,1024]
    float* out = (float*)d_out;                   // [2,2048,1024] fp32
    char* ws = (char*)d_ws;

    unsigned short* xn = (unsigned short*)(ws);              // 8 MB (reused as ao)
    unsigned short* wtq = (unsigned short*)(ws + 8388608);   // 6 MB  [3072][1024]
    unsigned short* wto = (unsigned short*)(ws + 14680064);  // 2 MB  [1024][1024]
    unsigned short* qw = (unsigned short*)(ws + 16777216);   // 8 MB  [32][2048][64]
    unsigned short* kw = (unsigned short*)(ws + 25165824);   // 8 MB  [32][2048][64]
    unsigned short* vw = (unsigned short*)(ws + 33554432);   // 8 MB  [32][64][2048]
    unsigned short* ao = xn;                                 // reuse after QKV GEMM

    prep_k<<<8192, 256, 0, stream>>>(x, gamma, w_qkv, w_out, xn, wtq, wto);
    gemm_bt_k<1, 128><<<dim3(24, 32), 256, 0, stream>>>(xn, wtq, nullptr, qw, kw, vw,
                                                        4096, 3072, 1024);
    attn_k<<<dim3(32, 32), 256, 0, stream>>>(qw, kw, vw, ao);
    gemm_bt_k<0, 64><<<dim3(8, 64), 256, 0, stream>>>(ao, wto, out, nullptr, nullptr,
                                                      nullptr, 4096, 1024, 1024);
}

// Round 4
// 216.875 us; speedup vs baseline: 1.6252x; 1.6252x over previous
//
#include <hip/hip_runtime.h>
#include <hip/hip_bf16.h>

typedef __bf16 bf16x8 __attribute__((ext_vector_type(8)));
typedef short s16x4 __attribute__((ext_vector_type(4)));
typedef float f32x4 __attribute__((ext_vector_type(4)));
typedef unsigned short u16x8 __attribute__((ext_vector_type(8)));

#define MFMA_K32(a, b, c) __builtin_amdgcn_mfma_f32_16x16x32_bf16(a, b, c, 0, 0, 0)

// 16x16x16 bf16 MFMA; builtin exists only in device pass.
static __device__ __forceinline__ f32x4 mfma_k16(s16x4 a, s16x4 b, f32x4 c) {
#ifdef __HIP_DEVICE_COMPILE__
    return __builtin_amdgcn_mfma_f32_16x16x16bf16_1k(a, b, c, 0, 0, 0);
#else
    return c;
#endif
}

static __device__ __forceinline__ float fast_exp2(float x) {
#ifdef __HIP_DEVICE_COMPILE__
    return __builtin_amdgcn_exp2f(x);
#else
    return x;
#endif
}

static __device__ __forceinline__ void prio_hi() {
#ifdef __HIP_DEVICE_COMPILE__
    __builtin_amdgcn_s_setprio(1);
#endif
}
static __device__ __forceinline__ void prio_lo() {
#ifdef __HIP_DEVICE_COMPILE__
    __builtin_amdgcn_s_setprio(0);
#endif
}

// async global->LDS, 16B per lane; lds dest = wave-uniform base + lane*16
#define GLL16(gp, lp)                                              \
    __builtin_amdgcn_global_load_lds(                              \
        (const __attribute__((address_space(1))) void*)(gp),       \
        (__attribute__((address_space(3))) void*)(lp), 16, 0, 0)

// round-to-nearest-even fp32 -> bf16 (finite inputs only)
static __device__ __forceinline__ unsigned short f2bf(float f) {
    unsigned int u = __float_as_uint(f);
    u += 0x7fffu + ((u >> 16) & 1u);
    return (unsigned short)(u >> 16);
}

// packed fp32x2 -> bf16x2 (RNE) via gfx950 v_cvt_pk_bf16_f32 when available
static __device__ __forceinline__ unsigned int cvtpk_bf16(float lo, float hi) {
#if defined(__HIP_DEVICE_COMPILE__) && __has_builtin(__builtin_amdgcn_cvt_pk_bf16_f32)
    typedef __bf16 bf16x2 __attribute__((ext_vector_type(2)));
    bf16x2 r = __builtin_amdgcn_cvt_pk_bf16_f32(lo, hi);
    return __builtin_bit_cast(unsigned int, r);
#else
    return (unsigned int)f2bf(lo) | ((unsigned int)f2bf(hi) << 16);
#endif
}

#define LOG2E 1.44269504088896340736f

// ---------------------------------------------------------------------------
// Fused prep: transpose+cast w_qkv and w_out, rmsnorm x -> xn (bf16).
// bid < 3072: w_qkv tile; < 4096: w_out tile; else rmsnorm row (bid-4096).
// ---------------------------------------------------------------------------
__global__ __launch_bounds__(256) void prep_k(
    const float* __restrict__ x, const float* __restrict__ gamma,
    const float* __restrict__ w_qkv, const float* __restrict__ w_out,
    unsigned short* __restrict__ xn, unsigned short* __restrict__ wtq,
    unsigned short* __restrict__ wto) {
    __shared__ float sm[32][33];
    int bid = blockIdx.x, tid = threadIdx.x;
    if (bid < 4096) {  // transpose paths (block-uniform branch)
        const float* in;
        unsigned short* out;
        int R = 1024, C, bx, by;
        if (bid < 3072) { in = w_qkv; out = wtq; C = 3072; bx = bid % 96; by = bid / 96; }
        else { int b2 = bid - 3072; in = w_out; out = wto; C = 1024; bx = b2 % 32; by = b2 / 32; }
        int c0 = bx * 32, r0 = by * 32;
        int tr = tid >> 5, tc = tid & 31;
#pragma unroll
        for (int i = 0; i < 4; i++)
            sm[tr + i * 8][tc] = in[(size_t)(r0 + tr + i * 8) * C + c0 + tc];
        __syncthreads();
#pragma unroll
        for (int i = 0; i < 4; i++)
            out[(size_t)(c0 + tr + i * 8) * R + r0 + tc] = f2bf(sm[tc][tr + i * 8]);
    } else {  // rmsnorm
        int row = bid - 4096;
        const float* xr = x + (size_t)row * 1024;
        float4 v = *(const float4*)(xr + tid * 4);
        float ss = v.x * v.x + v.y * v.y + v.z * v.z + v.w * v.w;
#pragma unroll
        for (int off = 1; off < 64; off <<= 1) ss += __shfl_xor(ss, off, 64);
        if ((tid & 63) == 0) sm[0][tid >> 6] = ss;
        __syncthreads();
        float tot = sm[0][0] + sm[0][1] + sm[0][2] + sm[0][3];
        float f = 32.0f / fmaxf(sqrtf(tot), 1e-12f);  // sqrt(1024)=32
        float4 g = *(const float4*)(gamma + tid * 4);
        uint2 o;
        o.x = cvtpk_bf16(v.x * f * g.x, v.y * f * g.y);
        o.y = cvtpk_bf16(v.z * f * g.z, v.w * f * g.w);
        *(uint2*)(xn + (size_t)row * 1024 + tid * 4) = o;
    }
}

// ---------------------------------------------------------------------------
// GEMM (m97 structure): C[M,N] = A[M,K] * BT[N,K]^T, bf16 in, fp32 acc.
// BM x 128 tile, BK=32, global_load_lds width-16 staging into unpadded LDS.
// BM=128: 4 waves 2x2 (4x4 frags). BM=64: 4 waves 1x4 (4x2 frags).
// MODE 0: fp32 store. MODE 1: qkv epilogue (q * scale*log2e for exp2-domain
// softmax; k in [bh][n][d]; v transposed to [bh][d][n]).
// ---------------------------------------------------------------------------
template <int MODE, int BM>
__global__ __launch_bounds__(256) void gemm_bt_k(
    const unsigned short* __restrict__ A, const unsigned short* __restrict__ BT,
    float* __restrict__ C, unsigned short* __restrict__ qw,
    unsigned short* __restrict__ kw, unsigned short* __restrict__ vw,
    int M, int N, int K) {
    constexpr int RT = 4;
    constexpr int CT = (BM == 128) ? 4 : 2;
    __shared__ unsigned short As[BM][32];
    __shared__ unsigned short Bs[128][32];
    int tid = threadIdx.x;
    int wave = tid >> 6, lane = tid & 63, quad = lane >> 4, l16 = lane & 15;
    int wrb, wcb;
    if constexpr (BM == 128) { wrb = (wave >> 1) * 64; wcb = (wave & 1) * 64; }
    else { wrb = 0; wcb = wave * 32; }
    int m0 = blockIdx.y * BM, n0 = blockIdx.x * 128;
    int lrow = lane >> 2, lcol = (lane & 3) * 8;  // lane -> (row,col) in 16x32 chunk
    const unsigned short *Ag0, *Ag1 = nullptr;
    if constexpr (BM == 128) {
        Ag0 = A + (size_t)(m0 + wave * 32 + lrow) * K + lcol;
        Ag1 = A + (size_t)(m0 + wave * 32 + 16 + lrow) * K + lcol;
    } else {
        Ag0 = A + (size_t)(m0 + wave * 16 + lrow) * K + lcol;
    }
    const unsigned short* Bg0 = BT + (size_t)(n0 + wave * 32 + lrow) * K + lcol;
    const unsigned short* Bg1 = BT + (size_t)(n0 + wave * 32 + 16 + lrow) * K + lcol;
    f32x4 acc[RT][CT] = {};
    for (int k0 = 0; k0 < K; k0 += 32) {
        __syncthreads();  // prior ds_reads done before overwrite
        if constexpr (BM == 128) {
            GLL16(Ag0 + k0, &As[wave * 32][0]);
            GLL16(Ag1 + k0, &As[wave * 32 + 16][0]);
        } else {
            GLL16(Ag0 + k0, &As[wave * 16][0]);
        }
        GLL16(Bg0 + k0, &Bs[wave * 32][0]);
        GLL16(Bg1 + k0, &Bs[wave * 32 + 16][0]);
        __syncthreads();  // drains vmcnt: staging complete
        bf16x8 af[RT], bfr[CT];
#pragma unroll
        for (int t = 0; t < RT; t++)
            af[t] = *(const bf16x8*)&As[wrb + t * 16 + l16][quad * 8];
#pragma unroll
        for (int t = 0; t < CT; t++)
            bfr[t] = *(const bf16x8*)&Bs[wcb + t * 16 + l16][quad * 8];
#pragma unroll
        for (int rt = 0; rt < RT; rt++)
#pragma unroll
            for (int ct = 0; ct < CT; ct++)
                acc[rt][ct] = MFMA_K32(af[rt], bfr[ct], acc[rt][ct]);
    }
#pragma unroll
    for (int rt = 0; rt < RT; rt++) {
        int mb = m0 + wrb + rt * 16 + quad * 4;
        int b = mb >> 11, nn = mb & 2047;
#pragma unroll
        for (int ct = 0; ct < CT; ct++) {
            int col = n0 + wcb + ct * 16 + l16;
            if (MODE == 0) {
#pragma unroll
                for (int r = 0; r < 4; r++)
                    C[(size_t)(mb + r) * N + col] = acc[rt][ct][r];
            } else {
                int sec = col >> 10, ci = col & 1023;
                int hh = ci >> 6, dd = ci & 63;
                int bh = b * 16 + hh;
                if (sec == 0) {
#pragma unroll
                    for (int r = 0; r < 4; r++)
                        qw[((size_t)bh * 2048 + nn + r) * 64 + dd] =
                            f2bf(acc[rt][ct][r] * (0.125f * LOG2E));
                } else if (sec == 1) {
#pragma unroll
                    for (int r = 0; r < 4; r++)
                        kw[((size_t)bh * 2048 + nn + r) * 64 + dd] = f2bf(acc[rt][ct][r]);
                } else {
                    uint2 pk;
                    pk.x = cvtpk_bf16(acc[rt][ct][0], acc[rt][ct][1]);
                    pk.y = cvtpk_bf16(acc[rt][ct][2], acc[rt][ct][3]);
                    *(uint2*)&vw[((size_t)bh * 64 + dd) * 2048 + nn] = pk;
                }
            }
        }
    }
}

// ---------------------------------------------------------------------------
// Causal flash attention (round 4): R2 machinery, 32 q-rows per wave.
// R3 post-mortem: direct-from-global fragments = uncoalesced V gathers + no
// software pipeline -> MfmaUtil 4.7%, 216us. The reg-prefetch+dbuf+LDS
// structure IS the latency hiding; restored here.
// R2 model: ~20 DS ops (~10.5KB LDS traffic) per 16q x 32k wave-tile ->
// ~60% of kernel cycles on the per-CU DS pipe (incl. 7.6M conflict cycles
// ~ shuffles); occupancy 25->50% bought nothing (R0 vs R2). So: halve DS
// work per unit by having each wave own 32 q-rows (two 16-row halves h2).
// ak/av fragment reads, staging, and barriers are shared across h2 (DS
// bytes per 16q-unit ~10.5 -> ~5.3KB); sum-reduce shuffles deferred to
// epilogue (per-lane lrun, validated in R3) -> 2 shuffles/tile not 4, and
// the sum leaves the per-tile dependent chain.
// Grid (32 bh, 16 qb): block = 128 q-rows, 4 waves x 32q. nT = 4qb+4 tiles
// of 32 keys; wave w active while t <= 4qb+w (mask at t == 4qb+w), idle
// waves still stage+barrier. Heavy-first LPT. 2048 waves -> ~25% occupancy
// ceiling (accepted: occupancy proved not the lever).
// __launch_bounds__(256,3): ~125 VGPR est < 168 cap, no spill (R1 lesson);
// occupancy is block-count-bound (2 blocks/CU) so the relaxed cap is free.
// T13 defer-max (with lrun*=al), T5 setprio around MFMA clusters.
// ---------------------------------------------------------------------------
__global__ __launch_bounds__(256, 3) void attn_k(
    const unsigned short* __restrict__ q, const unsigned short* __restrict__ k,
    const unsigned short* __restrict__ vt, unsigned short* __restrict__ o) {
    typedef unsigned short ush;
    __shared__ ush Ks[2][32][72];  // [buf][key][d]   9216 B
    __shared__ ush Vt[2][64][40];  // [buf][d][key]  10240 B
    int bh = blockIdx.x;
    int qb = 15 - (int)blockIdx.y;  // heavy-first LPT order
    int tid = threadIdx.x, wave = tid >> 6, lane = tid & 63;
    int quad = lane >> 4, l16 = lane & 15;
    int b = bh >> 4, h = bh & 15;
    const ush* qg = q + (size_t)bh * 2048 * 64;
    const ush* kg = k + (size_t)bh * 2048 * 64;
    const ush* vg = vt + (size_t)bh * 64 * 2048;

    // staging map (256 threads, one u16x8 each): K 32x64, V 64x32 per tile
    int kr = tid >> 3, kc = (tid & 7) * 8;
    int vr = tid >> 2, vc = (tid & 3) * 8;
    const ush* Kg = kg + (size_t)kr * 64 + kc;    // + t*2048
    const ush* Vg = vg + (size_t)vr * 2048 + vc;  // + t*32

    int rbase = qb * 128 + wave * 32;  // this wave's 32 q-rows
    // Q^T B-operands for both halves: [k=d=ks*32+quad*8+j][n=qrow=l16]
    bf16x8 bq[2][2];  // [h2][ks]
#pragma unroll
    for (int h2 = 0; h2 < 2; h2++)
#pragma unroll
        for (int ks = 0; ks < 2; ks++)
            bq[h2][ks] =
                *(const bf16x8*)&qg[(size_t)(rbase + h2 * 16 + l16) * 64 + ks * 32 + quad * 8];

    f32x4 ot[2][4] = {};  // [h2][dt]: Ot C-layout [d=dt*16+quad*4+r][qrow=l16]
    float mrun[2] = {-1e30f, -1e30f};
    float lrun[2] = {0.f, 0.f};  // per-lane partials; reduced in epilogue
    int nT = 4 * qb + 4;
    int tmax = 4 * qb + wave;  // last tile this wave needs (masked)

    u16x8 pk, pv;  // prefetch registers
    pk = *(const u16x8*)(Kg);
    pv = *(const u16x8*)(Vg);
    *(u16x8*)&Ks[0][kr][kc] = pk;
    *(u16x8*)&Vt[0][vr][vc] = pv;
    __syncthreads();

    for (int t = 0; t < nT; t++) {
        int cb = t & 1;
        bool pf = (t + 1 < nT);
        if (pf) {  // issue next tile's global loads early
            pk = *(const u16x8*)(Kg + (size_t)(t + 1) * 2048);
            pv = *(const u16x8*)(Vg + (t + 1) * 32);
        }
        if (t <= tmax) {  // wave-uniform active check
            // K fragments (shared across both q-halves)
            bf16x8 ak[2][2];  // [ct][ks]
#pragma unroll
            for (int ct = 0; ct < 2; ct++)
#pragma unroll
                for (int ks = 0; ks < 2; ks++)
                    ak[ct][ks] = *(const bf16x8*)&Ks[cb][ct * 16 + l16][ks * 32 + quad * 8];
            // St[key=ct*16+quad*4+r][qrow=l16] = K . Q^T, both halves
            f32x4 sf[2][2];  // [h2][ct]
            prio_hi();
#pragma unroll
            for (int h2 = 0; h2 < 2; h2++)
#pragma unroll
                for (int ct = 0; ct < 2; ct++) {
                    f32x4 s = {};
                    s = MFMA_K32(ak[ct][0], bq[h2][0], s);
                    s = MFMA_K32(ak[ct][1], bq[h2][1], s);
                    sf[h2][ct] = s;
                }
            prio_lo();
            if (t == tmax) {  // diagonal tile: causal mask (local indices)
#pragma unroll
                for (int h2 = 0; h2 < 2; h2++)
#pragma unroll
                    for (int ct = 0; ct < 2; ct++)
#pragma unroll
                        for (int r = 0; r < 4; r++)
                            if (ct * 16 + quad * 4 + r > h2 * 16 + l16)
                                sf[h2][ct][r] = -1e30f;
            }
            // V fragments (shared across halves) — issue before softmax so
            // the b64 latency overlaps the VALU chain
            s16x4 av[4][2];  // [dt][ct]
#pragma unroll
            for (int dt = 0; dt < 4; dt++)
#pragma unroll
                for (int ct = 0; ct < 2; ct++)
                    av[dt][ct] = *(const s16x4*)&Vt[cb][dt * 16 + l16][ct * 16 + quad * 4];
            // online softmax per half (exp2 domain; log2e pre-folded into q)
            s16x4 bpr[2][2];  // [h2][ct]
#pragma unroll
            for (int h2 = 0; h2 < 2; h2++) {
                float m0 = fmaxf(fmaxf(sf[h2][0][0], sf[h2][0][1]),
                                 fmaxf(sf[h2][0][2], sf[h2][0][3]));
                float m1 = fmaxf(fmaxf(sf[h2][1][0], sf[h2][1][1]),
                                 fmaxf(sf[h2][1][2], sf[h2][1][3]));
                float mx = fmaxf(m0, m1);
                mx = fmaxf(mx, __shfl_xor(mx, 16, 64));
                mx = fmaxf(mx, __shfl_xor(mx, 32, 64));
                // T13 defer-max: rescale only when max really grew (P<=2^8 ok)
                if (mx > mrun[h2] + 8.0f) {
                    float al = fast_exp2(mrun[h2] - mx);
                    mrun[h2] = mx;
                    lrun[h2] *= al;
#pragma unroll
                    for (int dt = 0; dt < 4; dt++)
#pragma unroll
                        for (int r = 0; r < 4; r++) ot[h2][dt][r] *= al;
                }
                float rs = 0.f;
#pragma unroll
                for (int ct = 0; ct < 2; ct++)
#pragma unroll
                    for (int r = 0; r < 4; r++) {
                        float p = fast_exp2(sf[h2][ct][r] - mrun[h2]);
                        sf[h2][ct][r] = p;
                        rs += p;
                    }
                lrun[h2] += rs;  // per-lane; cross-quad reduce deferred
                // P -> packed bf16 B-fragments (k=quad*4+j = C-layout)
#pragma unroll
                for (int ct = 0; ct < 2; ct++) {
                    uint2 u;
                    u.x = cvtpk_bf16(sf[h2][ct][0], sf[h2][ct][1]);
                    u.y = cvtpk_bf16(sf[h2][ct][2], sf[h2][ct][3]);
                    bpr[h2][ct] = __builtin_bit_cast(s16x4, u);
                }
            }
            // Ot += V^T * P^T, both halves
            prio_hi();
#pragma unroll
            for (int h2 = 0; h2 < 2; h2++)
#pragma unroll
                for (int dt = 0; dt < 4; dt++)
#pragma unroll
                    for (int ct = 0; ct < 2; ct++)
                        ot[h2][dt] = mfma_k16(av[dt][ct], bpr[h2][ct], ot[h2][dt]);
            prio_lo();
        }
        if (pf) {  // write prefetched tile to the other buffer
            *(u16x8*)&Ks[1 - cb][kr][kc] = pk;
            *(u16x8*)&Vt[1 - cb][vr][vc] = pv;
        }
        __syncthreads();  // single barrier per tile
    }

    // epilogue: deferred cross-quad sum reduce, normalize, store
#pragma unroll
    for (int h2 = 0; h2 < 2; h2++) {
        float l = lrun[h2];
        l += __shfl_xor(l, 16, 64);
        l += __shfl_xor(l, 32, 64);
        float inv = 1.0f / l;
        size_t rowbase = ((size_t)b * 2048 + rbase + h2 * 16 + l16) * 1024 + h * 64;
#pragma unroll
        for (int dt = 0; dt < 4; dt++) {
            uint2 pkk;
            pkk.x = cvtpk_bf16(ot[h2][dt][0] * inv, ot[h2][dt][1] * inv);
            pkk.y = cvtpk_bf16(ot[h2][dt][2] * inv, ot[h2][dt][3] * inv);
            *(uint2*)&o[rowbase + dt * 16 + quad * 4] = pkk;
        }
    }
}

extern "C" void kernel_launch(void* const* d_in, const int* in_sizes, int n_in,
                              void* d_out, int out_size, void* d_ws, size_t ws_size,
                              hipStream_t stream) {
    const float* x = (const float*)d_in[0];       // [2,2048,1024]
    const float* gamma = (const float*)d_in[1];   // [1024]
    const float* w_qkv = (const float*)d_in[2];   // [1024,3072]
    const float* w_out = (const float*)d_in[3];   // [1024,1024]
    float* out = (float*)d_out;                   // [2,2048,1024] fp32
    char* ws = (char*)d_ws;

    unsigned short* xn = (unsigned short*)(ws);              // 8 MB (reused as ao)
    unsigned short* wtq = (unsigned short*)(ws + 8388608);   // 6 MB  [3072][1024]
    unsigned short* wto = (unsigned short*)(ws + 14680064);  // 2 MB  [1024][1024]
    unsigned short* qw = (unsigned short*)(ws + 16777216);   // 8 MB  [32][2048][64]
    unsigned short* kw = (unsigned short*)(ws + 25165824);   // 8 MB  [32][2048][64]
    unsigned short* vw = (unsigned short*)(ws + 33554432);   // 8 MB  [32][64][2048]
    unsigned short* ao = xn;                                 // reuse after QKV GEMM

    prep_k<<<8192, 256, 0, stream>>>(x, gamma, w_qkv, w_out, xn, wtq, wto);
    gemm_bt_k<1, 128><<<dim3(24, 32), 256, 0, stream>>>(xn, wtq, nullptr, qw, kw, vw,
                                                        4096, 3072, 1024);
    attn_k<<<dim3(32, 16), 256, 0, stream>>>(qw, kw, vw, ao);
    gemm_bt_k<0, 64><<<dim3(8, 64), 256, 0, stream>>>(ao, wto, out, nullptr, nullptr,
                                                      nullptr, 4096, 1024, 1024);
}

// Round 5
// 204.245 us; speedup vs baseline: 1.7256x; 1.0618x over previous
//
#include <hip/hip_runtime.h>
#include <hip/hip_bf16.h>

typedef __bf16 bf16x8 __attribute__((ext_vector_type(8)));
typedef short s16x4 __attribute__((ext_vector_type(4)));
typedef float f32x4 __attribute__((ext_vector_type(4)));
typedef unsigned short u16x8 __attribute__((ext_vector_type(8)));

#define MFMA_K32(a, b, c) __builtin_amdgcn_mfma_f32_16x16x32_bf16(a, b, c, 0, 0, 0)

// 16x16x16 bf16 MFMA; builtin exists only in device pass.
static __device__ __forceinline__ f32x4 mfma_k16(s16x4 a, s16x4 b, f32x4 c) {
#ifdef __HIP_DEVICE_COMPILE__
    return __builtin_amdgcn_mfma_f32_16x16x16bf16_1k(a, b, c, 0, 0, 0);
#else
    return c;
#endif
}

static __device__ __forceinline__ float fast_exp2(float x) {
#ifdef __HIP_DEVICE_COMPILE__
    return __builtin_amdgcn_exp2f(x);
#else
    return x;
#endif
}

static __device__ __forceinline__ void prio_hi() {
#ifdef __HIP_DEVICE_COMPILE__
    __builtin_amdgcn_s_setprio(1);
#endif
}
static __device__ __forceinline__ void prio_lo() {
#ifdef __HIP_DEVICE_COMPILE__
    __builtin_amdgcn_s_setprio(0);
#endif
}

// async global->LDS, 16B per lane; lds dest = wave-uniform base + lane*16
#define GLL16(gp, lp)                                              \
    __builtin_amdgcn_global_load_lds(                              \
        (const __attribute__((address_space(1))) void*)(gp),       \
        (__attribute__((address_space(3))) void*)(lp), 16, 0, 0)

// round-to-nearest-even fp32 -> bf16 (finite inputs only)
static __device__ __forceinline__ unsigned short f2bf(float f) {
    unsigned int u = __float_as_uint(f);
    u += 0x7fffu + ((u >> 16) & 1u);
    return (unsigned short)(u >> 16);
}

// packed fp32x2 -> bf16x2 (RNE) via gfx950 v_cvt_pk_bf16_f32 when available
static __device__ __forceinline__ unsigned int cvtpk_bf16(float lo, float hi) {
#if defined(__HIP_DEVICE_COMPILE__) && __has_builtin(__builtin_amdgcn_cvt_pk_bf16_f32)
    typedef __bf16 bf16x2 __attribute__((ext_vector_type(2)));
    bf16x2 r = __builtin_amdgcn_cvt_pk_bf16_f32(lo, hi);
    return __builtin_bit_cast(unsigned int, r);
#else
    return (unsigned int)f2bf(lo) | ((unsigned int)f2bf(hi) << 16);
#endif
}

#define LOG2E 1.44269504088896340736f

// ---------------------------------------------------------------------------
// Fused prep: transpose+cast w_qkv and w_out, rmsnorm x -> xn (bf16).
// bid < 3072: w_qkv tile; < 4096: w_out tile; else rmsnorm row (bid-4096).
// ---------------------------------------------------------------------------
__global__ __launch_bounds__(256) void prep_k(
    const float* __restrict__ x, const float* __restrict__ gamma,
    const float* __restrict__ w_qkv, const float* __restrict__ w_out,
    unsigned short* __restrict__ xn, unsigned short* __restrict__ wtq,
    unsigned short* __restrict__ wto) {
    __shared__ float sm[32][33];
    int bid = blockIdx.x, tid = threadIdx.x;
    if (bid < 4096) {  // transpose paths (block-uniform branch)
        const float* in;
        unsigned short* out;
        int R = 1024, C, bx, by;
        if (bid < 3072) { in = w_qkv; out = wtq; C = 3072; bx = bid % 96; by = bid / 96; }
        else { int b2 = bid - 3072; in = w_out; out = wto; C = 1024; bx = b2 % 32; by = b2 / 32; }
        int c0 = bx * 32, r0 = by * 32;
        int tr = tid >> 5, tc = tid & 31;
#pragma unroll
        for (int i = 0; i < 4; i++)
            sm[tr + i * 8][tc] = in[(size_t)(r0 + tr + i * 8) * C + c0 + tc];
        __syncthreads();
#pragma unroll
        for (int i = 0; i < 4; i++)
            out[(size_t)(c0 + tr + i * 8) * R + r0 + tc] = f2bf(sm[tc][tr + i * 8]);
    } else {  // rmsnorm
        int row = bid - 4096;
        const float* xr = x + (size_t)row * 1024;
        float4 v = *(const float4*)(xr + tid * 4);
        float ss = v.x * v.x + v.y * v.y + v.z * v.z + v.w * v.w;
#pragma unroll
        for (int off = 1; off < 64; off <<= 1) ss += __shfl_xor(ss, off, 64);
        if ((tid & 63) == 0) sm[0][tid >> 6] = ss;
        __syncthreads();
        float tot = sm[0][0] + sm[0][1] + sm[0][2] + sm[0][3];
        float f = 32.0f / fmaxf(sqrtf(tot), 1e-12f);  // sqrt(1024)=32
        float4 g = *(const float4*)(gamma + tid * 4);
        uint2 o;
        o.x = cvtpk_bf16(v.x * f * g.x, v.y * f * g.y);
        o.y = cvtpk_bf16(v.z * f * g.z, v.w * f * g.w);
        *(uint2*)(xn + (size_t)row * 1024 + tid * 4) = o;
    }
}

// ---------------------------------------------------------------------------
// GEMM (m97 structure): C[M,N] = A[M,K] * BT[N,K]^T, bf16 in, fp32 acc.
// BM x 128 tile, BK=32, global_load_lds width-16 staging into unpadded LDS.
// BM=128: 4 waves 2x2 (4x4 frags). BM=64: 4 waves 1x4 (4x2 frags).
// MODE 0: fp32 store. MODE 1: qkv epilogue (q * scale*log2e for exp2-domain
// softmax; k in [bh][n][d]; v transposed to [bh][d][n]).
// ---------------------------------------------------------------------------
template <int MODE, int BM>
__global__ __launch_bounds__(256) void gemm_bt_k(
    const unsigned short* __restrict__ A, const unsigned short* __restrict__ BT,
    float* __restrict__ C, unsigned short* __restrict__ qw,
    unsigned short* __restrict__ kw, unsigned short* __restrict__ vw,
    int M, int N, int K) {
    constexpr int RT = 4;
    constexpr int CT = (BM == 128) ? 4 : 2;
    __shared__ unsigned short As[BM][32];
    __shared__ unsigned short Bs[128][32];
    int tid = threadIdx.x;
    int wave = tid >> 6, lane = tid & 63, quad = lane >> 4, l16 = lane & 15;
    int wrb, wcb;
    if constexpr (BM == 128) { wrb = (wave >> 1) * 64; wcb = (wave & 1) * 64; }
    else { wrb = 0; wcb = wave * 32; }
    int m0 = blockIdx.y * BM, n0 = blockIdx.x * 128;
    int lrow = lane >> 2, lcol = (lane & 3) * 8;  // lane -> (row,col) in 16x32 chunk
    const unsigned short *Ag0, *Ag1 = nullptr;
    if constexpr (BM == 128) {
        Ag0 = A + (size_t)(m0 + wave * 32 + lrow) * K + lcol;
        Ag1 = A + (size_t)(m0 + wave * 32 + 16 + lrow) * K + lcol;
    } else {
        Ag0 = A + (size_t)(m0 + wave * 16 + lrow) * K + lcol;
    }
    const unsigned short* Bg0 = BT + (size_t)(n0 + wave * 32 + lrow) * K + lcol;
    const unsigned short* Bg1 = BT + (size_t)(n0 + wave * 32 + 16 + lrow) * K + lcol;
    f32x4 acc[RT][CT] = {};
    for (int k0 = 0; k0 < K; k0 += 32) {
        __syncthreads();  // prior ds_reads done before overwrite
        if constexpr (BM == 128) {
            GLL16(Ag0 + k0, &As[wave * 32][0]);
            GLL16(Ag1 + k0, &As[wave * 32 + 16][0]);
        } else {
            GLL16(Ag0 + k0, &As[wave * 16][0]);
        }
        GLL16(Bg0 + k0, &Bs[wave * 32][0]);
        GLL16(Bg1 + k0, &Bs[wave * 32 + 16][0]);
        __syncthreads();  // drains vmcnt: staging complete
        bf16x8 af[RT], bfr[CT];
#pragma unroll
        for (int t = 0; t < RT; t++)
            af[t] = *(const bf16x8*)&As[wrb + t * 16 + l16][quad * 8];
#pragma unroll
        for (int t = 0; t < CT; t++)
            bfr[t] = *(const bf16x8*)&Bs[wcb + t * 16 + l16][quad * 8];
#pragma unroll
        for (int rt = 0; rt < RT; rt++)
#pragma unroll
            for (int ct = 0; ct < CT; ct++)
                acc[rt][ct] = MFMA_K32(af[rt], bfr[ct], acc[rt][ct]);
    }
#pragma unroll
    for (int rt = 0; rt < RT; rt++) {
        int mb = m0 + wrb + rt * 16 + quad * 4;
        int b = mb >> 11, nn = mb & 2047;
#pragma unroll
        for (int ct = 0; ct < CT; ct++) {
            int col = n0 + wcb + ct * 16 + l16;
            if (MODE == 0) {
#pragma unroll
                for (int r = 0; r < 4; r++)
                    C[(size_t)(mb + r) * N + col] = acc[rt][ct][r];
            } else {
                int sec = col >> 10, ci = col & 1023;
                int hh = ci >> 6, dd = ci & 63;
                int bh = b * 16 + hh;
                if (sec == 0) {
#pragma unroll
                    for (int r = 0; r < 4; r++)
                        qw[((size_t)bh * 2048 + nn + r) * 64 + dd] =
                            f2bf(acc[rt][ct][r] * (0.125f * LOG2E));
                } else if (sec == 1) {
#pragma unroll
                    for (int r = 0; r < 4; r++)
                        kw[((size_t)bh * 2048 + nn + r) * 64 + dd] = f2bf(acc[rt][ct][r]);
                } else {
                    uint2 pk;
                    pk.x = cvtpk_bf16(acc[rt][ct][0], acc[rt][ct][1]);
                    pk.y = cvtpk_bf16(acc[rt][ct][2], acc[rt][ct][3]);
                    *(uint2*)&vw[((size_t)bh * 64 + dd) * 2048 + nn] = pk;
                }
            }
        }
    }
}

// ---------------------------------------------------------------------------
// Causal flash attention, key-split 8-wave blocks (R2 structure restored).
// R4 post-mortem: 32q/wave over the full key range quadrupled the per-wave
// critical path (16q x 1024k -> 32q x 2048k) -> 76us. In a latency-bound
// triangular workload the longest serial wave-walk is the objective; R2's
// key-split minimizes it. This is R2 verbatim plus three validated deltas:
//  (1) lrun *= al inside defer-max (correctness fix; R2 shipped without it)
//  (2) deferred sum-reduce: lrun is a per-lane partial, the 2 sum-shuffles
//      per tile move to one pair in the epilogue (validated R3/R4)
//  (3) V fragments loaded right after QK^T so ds_read latency hides under
//      the softmax VALU chain (validated R4)
// Groups of 4 waves process key ranges [0,qt+1) / [qt+1,2qt+2) of 32-key
// tiles; merge via LDS (benign for fully-masked rows: a1 -> 0).
// (512,4): 128-reg budget, no spill (R1 lesson), 2 blocks/CU.
// ---------------------------------------------------------------------------
__global__ __launch_bounds__(512, 4) void attn_k(
    const unsigned short* __restrict__ q, const unsigned short* __restrict__ k,
    const unsigned short* __restrict__ vt, unsigned short* __restrict__ o) {
    // LDS union: [group][buf] K tiles (32x64, pad 72) + V tiles (64x32, pad 40);
    // epilogue overlays Osm[64][68] f32 on the K region, msm/lsm on V region.
    __shared__ __align__(16) char smem[38912];
    typedef unsigned short ush;
    ush(*Ks)[2][32][72] = (ush(*)[2][32][72])smem;            // 18432 B
    ush(*Vt)[2][64][40] = (ush(*)[2][64][40])(smem + 18432);  // 20480 B
    float(*Osm)[68] = (float(*)[68])smem;                     // 17408 B (<= K region)
    float* msm = (float*)(smem + 18432);                      // 256 B (in V region)
    float* lsm = msm + 64;

    int bh = blockIdx.x;
    int qt = 31 - (int)blockIdx.y;  // heavy-first LPT order
    int tid = threadIdx.x, wave = tid >> 6, lane = tid & 63;
    int quad = lane >> 4, l16 = lane & 15;
    int g = wave >> 2, wq = wave & 3;
    int b = bh >> 4, h = bh & 15;
    const ush* qg = q + (size_t)bh * 2048 * 64;
    const ush* kg = k + (size_t)bh * 2048 * 64;
    const ush* vg = vt + (size_t)bh * 64 * 2048;

    // staging map: 256 threads/group; K: 32 rows x 64 cols; V: 64 d x 32 keys
    int ti = wq * 64 + lane;
    int kr = ti >> 3, kc = (ti & 7) * 8;
    int vr = ti >> 2, vc = (ti & 3) * 8;
    const ush* Kg = kg + (size_t)kr * 64 + kc;
    const ush* Vg = vg + (size_t)vr * 2048 + vc;

    int row_l = wq * 16 + l16;    // local q row 0..63
    int q0w = qt * 64 + wq * 16;  // global q row base for this wave
    bf16x8 bq[2];                 // Q^T B-operand: [k=d=ks*32+quad*8+j][n=qrow=l16]
#pragma unroll
    for (int ks = 0; ks < 2; ks++)
        bq[ks] = *(const bf16x8*)&qg[(size_t)(q0w + l16) * 64 + ks * 32 + quad * 8];

    f32x4 ot[4] = {};                 // Ot C-layout: [d=dt*16+quad*4+r][qrow=l16]
    float mrun = -1e30f, lrun = 0.f;  // lrun is a PER-LANE partial (reduced at end)
    int nT = qt + 1;                  // tiles per group (equal for both groups)
    int kt0 = g ? (qt + 1) : 0;

    u16x8 pk, pv;  // prefetch registers
    // preload first tile into buf 0
    pk = *(const u16x8*)(Kg + (size_t)kt0 * 2048);
    pv = *(const u16x8*)(Vg + kt0 * 32);
    *(u16x8*)&Ks[g][0][kr][kc] = pk;
    *(u16x8*)&Vt[g][0][vr][vc] = pv;
    __syncthreads();

    for (int i = 0; i < nT; i++) {
        int cb = i & 1, kt = kt0 + i;
        bool pf = (i + 1 < nT);
        if (pf) {  // issue next tile's global loads early (wave-uniform branch)
            pk = *(const u16x8*)(Kg + (size_t)(kt + 1) * 2048);
            pv = *(const u16x8*)(Vg + (kt + 1) * 32);
        }
        // St[key=ct*16+quad*4+r][qrow=l16] = K . Q^T
        f32x4 sf[2];
        prio_hi();
#pragma unroll
        for (int ct = 0; ct < 2; ct++) {
            bf16x8 ak0 = *(const bf16x8*)&Ks[g][cb][ct * 16 + l16][quad * 8];
            bf16x8 ak1 = *(const bf16x8*)&Ks[g][cb][ct * 16 + l16][32 + quad * 8];
            f32x4 s = {};
            s = MFMA_K32(ak0, bq[0], s);
            s = MFMA_K32(ak1, bq[1], s);
            sf[ct] = s;
        }
        prio_lo();
        // V fragments early: ds_read latency overlaps the softmax VALU chain
        s16x4 av[4][2];
#pragma unroll
        for (int dt = 0; dt < 4; dt++)
#pragma unroll
            for (int ct = 0; ct < 2; ct++)
                av[dt][ct] = *(const s16x4*)&Vt[g][cb][dt * 16 + l16][ct * 16 + quad * 4];
        if (kt >= 2 * qt) {  // tiles that can touch the diagonal
#pragma unroll
            for (int ct = 0; ct < 2; ct++)
#pragma unroll
                for (int r = 0; r < 4; r++)
                    if (kt * 32 + ct * 16 + quad * 4 + r > qt * 64 + row_l)
                        sf[ct][r] = -1e30f;
        }
        // online softmax (exp2 domain; log2e pre-folded into q)
        float m0 = fmaxf(fmaxf(sf[0][0], sf[0][1]), fmaxf(sf[0][2], sf[0][3]));
        float m1 = fmaxf(fmaxf(sf[1][0], sf[1][1]), fmaxf(sf[1][2], sf[1][3]));
        float mx = fmaxf(m0, m1);
        mx = fmaxf(mx, __shfl_xor(mx, 16, 64));
        mx = fmaxf(mx, __shfl_xor(mx, 32, 64));
        // T13 defer-max: rescale only when max really grew (P <= 2^8 safe)
        if (mx > mrun + 8.0f) {
            float al = fast_exp2(mrun - mx);
            mrun = mx;
            lrun *= al;  // correctness: partial sum must track the new max
#pragma unroll
            for (int dt = 0; dt < 4; dt++)
#pragma unroll
                for (int r = 0; r < 4; r++) ot[dt][r] *= al;
        }
        float rs = 0.f;
#pragma unroll
        for (int ct = 0; ct < 2; ct++)
#pragma unroll
            for (int r = 0; r < 4; r++) {
                float p = fast_exp2(sf[ct][r] - mrun);
                sf[ct][r] = p;
                rs += p;
            }
        lrun += rs;  // per-lane partial; cross-quad reduce deferred to epilogue
        // P -> packed bf16 B-fragments for 16x16x16 (k=quad*4+j = C-layout)
        s16x4 bpr[2];
#pragma unroll
        for (int ct = 0; ct < 2; ct++) {
            uint2 u;
            u.x = cvtpk_bf16(sf[ct][0], sf[ct][1]);
            u.y = cvtpk_bf16(sf[ct][2], sf[ct][3]);
            bpr[ct] = __builtin_bit_cast(s16x4, u);
        }
        // Ot += V^T * P^T
        prio_hi();
#pragma unroll
        for (int dt = 0; dt < 4; dt++)
#pragma unroll
            for (int ct = 0; ct < 2; ct++)
                ot[dt] = mfma_k16(av[dt][ct], bpr[ct], ot[dt]);
        prio_lo();
        if (pf) {  // write prefetched tile to the other buffer
            *(u16x8*)&Ks[g][1 - cb][kr][kc] = pk;
            *(u16x8*)&Vt[g][1 - cb][vr][vc] = pv;
        }
        __syncthreads();  // single barrier per tile
    }

    // deferred cross-quad sum reduce (was 2 shuffles per tile, now once)
    lrun += __shfl_xor(lrun, 16, 64);
    lrun += __shfl_xor(lrun, 32, 64);

    // ---- cross-group merge (group 1 -> LDS, group 0 combines + writes) ----
    if (g == 1) {
        msm[row_l] = mrun;  // quads duplicate-write identical values: benign
        lsm[row_l] = lrun;
#pragma unroll
        for (int dt = 0; dt < 4; dt++)
            *(f32x4*)&Osm[row_l][dt * 16 + quad * 4] = ot[dt];
    }
    __syncthreads();
    if (g == 0) {
        float m1 = msm[row_l], l1 = lsm[row_l];
        float mmax = fmaxf(mrun, m1);
        float a0 = fast_exp2(mrun - mmax), a1 = fast_exp2(m1 - mmax);
        float inv = 1.0f / (a0 * lrun + a1 * l1);
        float s0 = a0 * inv, s1 = a1 * inv;
        size_t rowbase = ((size_t)b * 2048 + qt * 64 + row_l) * 1024 + h * 64;
#pragma unroll
        for (int dt = 0; dt < 4; dt++) {
            f32x4 o1 = *(const f32x4*)&Osm[row_l][dt * 16 + quad * 4];
            uint2 pkk;
            pkk.x = cvtpk_bf16(ot[dt][0] * s0 + o1[0] * s1,
                               ot[dt][1] * s0 + o1[1] * s1);
            pkk.y = cvtpk_bf16(ot[dt][2] * s0 + o1[2] * s1,
                               ot[dt][3] * s0 + o1[3] * s1);
            *(uint2*)&o[rowbase + dt * 16 + quad * 4] = pkk;
        }
    }
}

extern "C" void kernel_launch(void* const* d_in, const int* in_sizes, int n_in,
                              void* d_out, int out_size, void* d_ws, size_t ws_size,
                              hipStream_t stream) {
    const float* x = (const float*)d_in[0];       // [2,2048,1024]
    const float* gamma = (const float*)d_in[1];   // [1024]
    const float* w_qkv = (const float*)d_in[2];   // [1024,3072]
    const float* w_out = (const float*)d_in[3];   // [1024,1024]
    float* out = (float*)d_out;                   // [2,2048,1024] fp32
    char* ws = (char*)d_ws;

    unsigned short* xn = (unsigned short*)(ws);              // 8 MB (reused as ao)
    unsigned short* wtq = (unsigned short*)(ws + 8388608);   // 6 MB  [3072][1024]
    unsigned short* wto = (unsigned short*)(ws + 14680064);  // 2 MB  [1024][1024]
    unsigned short* qw = (unsigned short*)(ws + 16777216);   // 8 MB  [32][2048][64]
    unsigned short* kw = (unsigned short*)(ws + 25165824);   // 8 MB  [32][2048][64]
    unsigned short* vw = (unsigned short*)(ws + 33554432);   // 8 MB  [32][64][2048]
    unsigned short* ao = xn;                                 // reuse after QKV GEMM

    prep_k<<<8192, 256, 0, stream>>>(x, gamma, w_qkv, w_out, xn, wtq, wto);
    gemm_bt_k<1, 128><<<dim3(24, 32), 256, 0, stream>>>(xn, wtq, nullptr, qw, kw, vw,
                                                        4096, 3072, 1024);
    attn_k<<<dim3(32, 32), 512, 0, stream>>>(qw, kw, vw, ao);
    // BM=128 (2x2 waves, 16 MFMA/K-step) instead of BM=64 (8 MFMA/K-step at
    // the same staging+barrier cost): the 343 vs 912 TF regime on the ladder.
    gemm_bt_k<0, 128><<<dim3(8, 32), 256, 0, stream>>>(ao, wto, out, nullptr, nullptr,
                                                       nullptr, 4096, 1024, 1024);
}

// Round 6
// 187.863 us; speedup vs baseline: 1.8761x; 1.0872x over previous
//
#include <hip/hip_runtime.h>
#include <hip/hip_bf16.h>

typedef __bf16 bf16x8 __attribute__((ext_vector_type(8)));
typedef short s16x4 __attribute__((ext_vector_type(4)));
typedef float f32x4 __attribute__((ext_vector_type(4)));
typedef unsigned short u16x8 __attribute__((ext_vector_type(8)));

#define MFMA_K32(a, b, c) __builtin_amdgcn_mfma_f32_16x16x32_bf16(a, b, c, 0, 0, 0)

// 16x16x16 bf16 MFMA; builtin exists only in device pass.
static __device__ __forceinline__ f32x4 mfma_k16(s16x4 a, s16x4 b, f32x4 c) {
#ifdef __HIP_DEVICE_COMPILE__
    return __builtin_amdgcn_mfma_f32_16x16x16bf16_1k(a, b, c, 0, 0, 0);
#else
    return c;
#endif
}

static __device__ __forceinline__ float fast_exp2(float x) {
#ifdef __HIP_DEVICE_COMPILE__
    return __builtin_amdgcn_exp2f(x);
#else
    return x;
#endif
}

static __device__ __forceinline__ void prio_hi() {
#ifdef __HIP_DEVICE_COMPILE__
    __builtin_amdgcn_s_setprio(1);
#endif
}
static __device__ __forceinline__ void prio_lo() {
#ifdef __HIP_DEVICE_COMPILE__
    __builtin_amdgcn_s_setprio(0);
#endif
}

// async global->LDS, 16B per lane; lds dest = wave-uniform base + lane*16
#define GLL16(gp, lp)                                              \
    __builtin_amdgcn_global_load_lds(                              \
        (const __attribute__((address_space(1))) void*)(gp),       \
        (__attribute__((address_space(3))) void*)(lp), 16, 0, 0)

// round-to-nearest-even fp32 -> bf16 (finite inputs only)
static __device__ __forceinline__ unsigned short f2bf(float f) {
    unsigned int u = __float_as_uint(f);
    u += 0x7fffu + ((u >> 16) & 1u);
    return (unsigned short)(u >> 16);
}

// packed fp32x2 -> bf16x2 (RNE) via gfx950 v_cvt_pk_bf16_f32 when available
static __device__ __forceinline__ unsigned int cvtpk_bf16(float lo, float hi) {
#if defined(__HIP_DEVICE_COMPILE__) && __has_builtin(__builtin_amdgcn_cvt_pk_bf16_f32)
    typedef __bf16 bf16x2 __attribute__((ext_vector_type(2)));
    bf16x2 r = __builtin_amdgcn_cvt_pk_bf16_f32(lo, hi);
    return __builtin_bit_cast(unsigned int, r);
#else
    return (unsigned int)f2bf(lo) | ((unsigned int)f2bf(hi) << 16);
#endif
}

#define LOG2E 1.44269504088896340736f

// ---------------------------------------------------------------------------
// Fused prep: transpose+cast w_qkv and w_out, rmsnorm x -> xn (bf16).
// bid < 3072: w_qkv tile; < 4096: w_out tile; else rmsnorm row (bid-4096).
// ---------------------------------------------------------------------------
__global__ __launch_bounds__(256) void prep_k(
    const float* __restrict__ x, const float* __restrict__ gamma,
    const float* __restrict__ w_qkv, const float* __restrict__ w_out,
    unsigned short* __restrict__ xn, unsigned short* __restrict__ wtq,
    unsigned short* __restrict__ wto) {
    __shared__ float sm[32][33];
    int bid = blockIdx.x, tid = threadIdx.x;
    if (bid < 4096) {  // transpose paths (block-uniform branch)
        const float* in;
        unsigned short* out;
        int R = 1024, C, bx, by;
        if (bid < 3072) { in = w_qkv; out = wtq; C = 3072; bx = bid % 96; by = bid / 96; }
        else { int b2 = bid - 3072; in = w_out; out = wto; C = 1024; bx = b2 % 32; by = b2 / 32; }
        int c0 = bx * 32, r0 = by * 32;
        int tr = tid >> 5, tc = tid & 31;
#pragma unroll
        for (int i = 0; i < 4; i++)
            sm[tr + i * 8][tc] = in[(size_t)(r0 + tr + i * 8) * C + c0 + tc];
        __syncthreads();
#pragma unroll
        for (int i = 0; i < 4; i++)
            out[(size_t)(c0 + tr + i * 8) * R + r0 + tc] = f2bf(sm[tc][tr + i * 8]);
    } else {  // rmsnorm
        int row = bid - 4096;
        const float* xr = x + (size_t)row * 1024;
        float4 v = *(const float4*)(xr + tid * 4);
        float ss = v.x * v.x + v.y * v.y + v.z * v.z + v.w * v.w;
#pragma unroll
        for (int off = 1; off < 64; off <<= 1) ss += __shfl_xor(ss, off, 64);
        if ((tid & 63) == 0) sm[0][tid >> 6] = ss;
        __syncthreads();
        float tot = sm[0][0] + sm[0][1] + sm[0][2] + sm[0][3];
        float f = 32.0f / fmaxf(sqrtf(tot), 1e-12f);  // sqrt(1024)=32
        float4 g = *(const float4*)(gamma + tid * 4);
        uint2 o;
        o.x = cvtpk_bf16(v.x * f * g.x, v.y * f * g.y);
        o.y = cvtpk_bf16(v.z * f * g.z, v.w * f * g.w);
        *(uint2*)(xn + (size_t)row * 1024 + tid * 4) = o;
    }
}

// ---------------------------------------------------------------------------
// GEMM (m97 structure): C[M,N] = A[M,K] * BT[N,K]^T, bf16 in, fp32 acc.
// BM x 128 tile, BK=32, global_load_lds width-16 staging into unpadded LDS.
// BM=128: 4 waves 2x2 (4x4 frags). BM=64: 4 waves 1x4 (4x2 frags).
// MODE 0: fp32 store. MODE 1: qkv epilogue (q * scale*log2e for exp2-domain
// softmax; k in [bh][n][d]; v transposed to [bh][d][n]).
// R5 lesson: BM=128 on the 4096x1024 GEMM -> 256 blocks = 1 block/CU; the
// m97 structure needs >=2 co-resident blocks to cover its barrier drain.
// Keep BM=64 (512 blocks) for gemm2.
// ---------------------------------------------------------------------------
template <int MODE, int BM>
__global__ __launch_bounds__(256) void gemm_bt_k(
    const unsigned short* __restrict__ A, const unsigned short* __restrict__ BT,
    float* __restrict__ C, unsigned short* __restrict__ qw,
    unsigned short* __restrict__ kw, unsigned short* __restrict__ vw,
    int M, int N, int K) {
    constexpr int RT = 4;
    constexpr int CT = (BM == 128) ? 4 : 2;
    __shared__ unsigned short As[BM][32];
    __shared__ unsigned short Bs[128][32];
    int tid = threadIdx.x;
    int wave = tid >> 6, lane = tid & 63, quad = lane >> 4, l16 = lane & 15;
    int wrb, wcb;
    if constexpr (BM == 128) { wrb = (wave >> 1) * 64; wcb = (wave & 1) * 64; }
    else { wrb = 0; wcb = wave * 32; }
    int m0 = blockIdx.y * BM, n0 = blockIdx.x * 128;
    int lrow = lane >> 2, lcol = (lane & 3) * 8;  // lane -> (row,col) in 16x32 chunk
    const unsigned short *Ag0, *Ag1 = nullptr;
    if constexpr (BM == 128) {
        Ag0 = A + (size_t)(m0 + wave * 32 + lrow) * K + lcol;
        Ag1 = A + (size_t)(m0 + wave * 32 + 16 + lrow) * K + lcol;
    } else {
        Ag0 = A + (size_t)(m0 + wave * 16 + lrow) * K + lcol;
    }
    const unsigned short* Bg0 = BT + (size_t)(n0 + wave * 32 + lrow) * K + lcol;
    const unsigned short* Bg1 = BT + (size_t)(n0 + wave * 32 + 16 + lrow) * K + lcol;
    f32x4 acc[RT][CT] = {};
    for (int k0 = 0; k0 < K; k0 += 32) {
        __syncthreads();  // prior ds_reads done before overwrite
        if constexpr (BM == 128) {
            GLL16(Ag0 + k0, &As[wave * 32][0]);
            GLL16(Ag1 + k0, &As[wave * 32 + 16][0]);
        } else {
            GLL16(Ag0 + k0, &As[wave * 16][0]);
        }
        GLL16(Bg0 + k0, &Bs[wave * 32][0]);
        GLL16(Bg1 + k0, &Bs[wave * 32 + 16][0]);
        __syncthreads();  // drains vmcnt: staging complete
        bf16x8 af[RT], bfr[CT];
#pragma unroll
        for (int t = 0; t < RT; t++)
            af[t] = *(const bf16x8*)&As[wrb + t * 16 + l16][quad * 8];
#pragma unroll
        for (int t = 0; t < CT; t++)
            bfr[t] = *(const bf16x8*)&Bs[wcb + t * 16 + l16][quad * 8];
#pragma unroll
        for (int rt = 0; rt < RT; rt++)
#pragma unroll
            for (int ct = 0; ct < CT; ct++)
                acc[rt][ct] = MFMA_K32(af[rt], bfr[ct], acc[rt][ct]);
    }
#pragma unroll
    for (int rt = 0; rt < RT; rt++) {
        int mb = m0 + wrb + rt * 16 + quad * 4;
        int b = mb >> 11, nn = mb & 2047;
#pragma unroll
        for (int ct = 0; ct < CT; ct++) {
            int col = n0 + wcb + ct * 16 + l16;
            if (MODE == 0) {
#pragma unroll
                for (int r = 0; r < 4; r++)
                    C[(size_t)(mb + r) * N + col] = acc[rt][ct][r];
            } else {
                int sec = col >> 10, ci = col & 1023;
                int hh = ci >> 6, dd = ci & 63;
                int bh = b * 16 + hh;
                if (sec == 0) {
#pragma unroll
                    for (int r = 0; r < 4; r++)
                        qw[((size_t)bh * 2048 + nn + r) * 64 + dd] =
                            f2bf(acc[rt][ct][r] * (0.125f * LOG2E));
                } else if (sec == 1) {
#pragma unroll
                    for (int r = 0; r < 4; r++)
                        kw[((size_t)bh * 2048 + nn + r) * 64 + dd] = f2bf(acc[rt][ct][r]);
                } else {
                    uint2 pk;
                    pk.x = cvtpk_bf16(acc[rt][ct][0], acc[rt][ct][1]);
                    pk.y = cvtpk_bf16(acc[rt][ct][2], acc[rt][ct][3]);
                    *(uint2*)&vw[((size_t)bh * 64 + dd) * 2048 + nn] = pk;
                }
            }
        }
    }
}

// ---------------------------------------------------------------------------
// Causal flash attention, key-split 8-wave blocks (R2 structure, exact).
// R5 post-mortem: the R3/R4-"validated" V-hoist + per-tile restructure hurt
// on this structure (53->58us, VGPR 36->48) - cross-structure transfer
// fails; only within-structure A/B counts. This round: R2 body verbatim,
// ONE change: chain-cut softmax.
//   Per-tile chain was: QK -> fmax tree -> 2 dependent cross-quad shuffles
//   (DS round-trips, the longest serial segment, every tile) -> exp2 -> PV.
//   Now: per-lane max only; wave-uniform __any(mx_lane > mrun+8) ballot
//   (scalar, no DS) gates the full reduce+rescale (first tile, then rare).
//   Common path P = exp2(s - mrun) with stale row max, bounded by 2^8
//   (T13 tolerance). lrun becomes a per-lane partial, reduced once in the
//   epilogue (required by the chain-cut). Fully-masked rows still produce
//   P=1 garbage and are still killed by the merge (a1 -> 0), same as R2.
// Groups of 4 waves process key ranges [0,qt+1) / [qt+1,2qt+2) of 32-key
// tiles; merge via LDS. (512,4): 128-reg budget, no spill (R1 lesson).
// ---------------------------------------------------------------------------
__global__ __launch_bounds__(512, 4) void attn_k(
    const unsigned short* __restrict__ q, const unsigned short* __restrict__ k,
    const unsigned short* __restrict__ vt, unsigned short* __restrict__ o) {
    // LDS union: [group][buf] K tiles (32x64, pad 72) + V tiles (64x32, pad 40);
    // epilogue overlays Osm[64][68] f32 on the K region, msm/lsm on V region.
    __shared__ __align__(16) char smem[38912];
    typedef unsigned short ush;
    ush(*Ks)[2][32][72] = (ush(*)[2][32][72])smem;            // 18432 B
    ush(*Vt)[2][64][40] = (ush(*)[2][64][40])(smem + 18432);  // 20480 B
    float(*Osm)[68] = (float(*)[68])smem;                     // 17408 B (<= K region)
    float* msm = (float*)(smem + 18432);                      // 256 B (in V region)
    float* lsm = msm + 64;

    int bh = blockIdx.x;
    int qt = 31 - (int)blockIdx.y;  // heavy-first LPT order
    int tid = threadIdx.x, wave = tid >> 6, lane = tid & 63;
    int quad = lane >> 4, l16 = lane & 15;
    int g = wave >> 2, wq = wave & 3;
    int b = bh >> 4, h = bh & 15;
    const ush* qg = q + (size_t)bh * 2048 * 64;
    const ush* kg = k + (size_t)bh * 2048 * 64;
    const ush* vg = vt + (size_t)bh * 64 * 2048;

    // staging map: 256 threads/group; K: 32 rows x 64 cols; V: 64 d x 32 keys
    int ti = wq * 64 + lane;
    int kr = ti >> 3, kc = (ti & 7) * 8;
    int vr = ti >> 2, vc = (ti & 3) * 8;
    const ush* Kg = kg + (size_t)kr * 64 + kc;
    const ush* Vg = vg + (size_t)vr * 2048 + vc;

    int row_l = wq * 16 + l16;    // local q row 0..63
    int q0w = qt * 64 + wq * 16;  // global q row base for this wave
    bf16x8 bq[2];                 // Q^T B-operand: [k=d=ks*32+quad*8+j][n=qrow=l16]
#pragma unroll
    for (int ks = 0; ks < 2; ks++)
        bq[ks] = *(const bf16x8*)&qg[(size_t)(q0w + l16) * 64 + ks * 32 + quad * 8];

    f32x4 ot[4] = {};                 // Ot C-layout: [d=dt*16+quad*4+r][qrow=l16]
    float mrun = -1e30f, lrun = 0.f;  // lrun is a PER-LANE partial (reduced at end)
    int nT = qt + 1;                  // tiles per group (equal for both groups)
    int kt0 = g ? (qt + 1) : 0;

    u16x8 pk, pv;  // prefetch registers
    // preload first tile into buf 0
    pk = *(const u16x8*)(Kg + (size_t)kt0 * 2048);
    pv = *(const u16x8*)(Vg + kt0 * 32);
    *(u16x8*)&Ks[g][0][kr][kc] = pk;
    *(u16x8*)&Vt[g][0][vr][vc] = pv;
    __syncthreads();

    for (int i = 0; i < nT; i++) {
        int cb = i & 1, kt = kt0 + i;
        bool pf = (i + 1 < nT);
        if (pf) {  // issue next tile's global loads early (wave-uniform branch)
            pk = *(const u16x8*)(Kg + (size_t)(kt + 1) * 2048);
            pv = *(const u16x8*)(Vg + (kt + 1) * 32);
        }
        // St[key=ct*16+quad*4+r][qrow=l16] = K . Q^T
        f32x4 sf[2];
        prio_hi();
#pragma unroll
        for (int ct = 0; ct < 2; ct++) {
            bf16x8 ak0 = *(const bf16x8*)&Ks[g][cb][ct * 16 + l16][quad * 8];
            bf16x8 ak1 = *(const bf16x8*)&Ks[g][cb][ct * 16 + l16][32 + quad * 8];
            f32x4 s = {};
            s = MFMA_K32(ak0, bq[0], s);
            s = MFMA_K32(ak1, bq[1], s);
            sf[ct] = s;
        }
        prio_lo();
        if (kt >= 2 * qt) {  // tiles that can touch the diagonal
#pragma unroll
            for (int ct = 0; ct < 2; ct++)
#pragma unroll
                for (int r = 0; r < 4; r++)
                    if (kt * 32 + ct * 16 + quad * 4 + r > qt * 64 + row_l)
                        sf[ct][r] = -1e30f;
        }
        // chain-cut online softmax (exp2 domain; log2e pre-folded into q):
        // per-lane max only in the common path; no DS shuffles.
        float t0 = fmaxf(sf[0][0], sf[0][1]), t1 = fmaxf(sf[0][2], sf[0][3]);
        float t2 = fmaxf(sf[1][0], sf[1][1]), t3 = fmaxf(sf[1][2], sf[1][3]);
        float mx_l = fmaxf(fmaxf(t0, t1), fmaxf(t2, t3));
        if (__any(mx_l > mrun + 8.0f)) {  // rare: full reduce + rescale
            float mx = fmaxf(mx_l, __shfl_xor(mx_l, 16, 64));
            mx = fmaxf(mx, __shfl_xor(mx, 32, 64));
            float mnew = fmaxf(mrun, mx);
            float al = fast_exp2(mrun - mnew);
            mrun = mnew;
            lrun *= al;
#pragma unroll
            for (int dt = 0; dt < 4; dt++)
#pragma unroll
                for (int r = 0; r < 4; r++) ot[dt][r] *= al;
        }
        float rs = 0.f;
#pragma unroll
        for (int ct = 0; ct < 2; ct++)
#pragma unroll
            for (int r = 0; r < 4; r++) {
                float p = fast_exp2(sf[ct][r] - mrun);  // bounded by 2^8
                sf[ct][r] = p;
                rs += p;
            }
        lrun += rs;  // per-lane partial; cross-quad reduce deferred to epilogue
        // P -> packed bf16 B-fragments for 16x16x16 (k=quad*4+j = C-layout)
        s16x4 bpr[2];
#pragma unroll
        for (int ct = 0; ct < 2; ct++) {
            uint2 u;
            u.x = cvtpk_bf16(sf[ct][0], sf[ct][1]);
            u.y = cvtpk_bf16(sf[ct][2], sf[ct][3]);
            bpr[ct] = __builtin_bit_cast(s16x4, u);
        }
        // Ot += V^T * P^T
        prio_hi();
#pragma unroll
        for (int dt = 0; dt < 4; dt++) {
#pragma unroll
            for (int ct = 0; ct < 2; ct++) {
                s16x4 av = *(const s16x4*)&Vt[g][cb][dt * 16 + l16][ct * 16 + quad * 4];
                ot[dt] = mfma_k16(av, bpr[ct], ot[dt]);
            }
        }
        prio_lo();
        if (pf) {  // write prefetched tile to the other buffer
            *(u16x8*)&Ks[g][1 - cb][kr][kc] = pk;
            *(u16x8*)&Vt[g][1 - cb][vr][vc] = pv;
        }
        __syncthreads();  // single barrier per tile
    }

    // deferred cross-quad sum reduce (once, instead of 2 shuffles per tile)
    lrun += __shfl_xor(lrun, 16, 64);
    lrun += __shfl_xor(lrun, 32, 64);

    // ---- cross-group merge (group 1 -> LDS, group 0 combines + writes) ----
    if (g == 1) {
        msm[row_l] = mrun;  // quads duplicate-write identical values: benign
        lsm[row_l] = lrun;
#pragma unroll
        for (int dt = 0; dt < 4; dt++)
            *(f32x4*)&Osm[row_l][dt * 16 + quad * 4] = ot[dt];
    }
    __syncthreads();
    if (g == 0) {
        float m1 = msm[row_l], l1 = lsm[row_l];
        float mmax = fmaxf(mrun, m1);
        float a0 = fast_exp2(mrun - mmax), a1 = fast_exp2(m1 - mmax);
        float inv = 1.0f / (a0 * lrun + a1 * l1);
        float s0 = a0 * inv, s1 = a1 * inv;
        size_t rowbase = ((size_t)b * 2048 + qt * 64 + row_l) * 1024 + h * 64;
#pragma unroll
        for (int dt = 0; dt < 4; dt++) {
            f32x4 o1 = *(const f32x4*)&Osm[row_l][dt * 16 + quad * 4];
            uint2 pkk;
            pkk.x = cvtpk_bf16(ot[dt][0] * s0 + o1[0] * s1,
                               ot[dt][1] * s0 + o1[1] * s1);
            pkk.y = cvtpk_bf16(ot[dt][2] * s0 + o1[2] * s1,
                               ot[dt][3] * s0 + o1[3] * s1);
            *(uint2*)&o[rowbase + dt * 16 + quad * 4] = pkk;
        }
    }
}

extern "C" void kernel_launch(void* const* d_in, const int* in_sizes, int n_in,
                              void* d_out, int out_size, void* d_ws, size_t ws_size,
                              hipStream_t stream) {
    const float* x = (const float*)d_in[0];       // [2,2048,1024]
    const float* gamma = (const float*)d_in[1];   // [1024]
    const float* w_qkv = (const float*)d_in[2];   // [1024,3072]
    const float* w_out = (const float*)d_in[3];   // [1024,1024]
    float* out = (float*)d_out;                   // [2,2048,1024] fp32
    char* ws = (char*)d_ws;

    unsigned short* xn = (unsigned short*)(ws);              // 8 MB (reused as ao)
    unsigned short* wtq = (unsigned short*)(ws + 8388608);   // 6 MB  [3072][1024]
    unsigned short* wto = (unsigned short*)(ws + 14680064);  // 2 MB  [1024][1024]
    unsigned short* qw = (unsigned short*)(ws + 16777216);   // 8 MB  [32][2048][64]
    unsigned short* kw = (unsigned short*)(ws + 25165824);   // 8 MB  [32][2048][64]
    unsigned short* vw = (unsigned short*)(ws + 33554432);   // 8 MB  [32][64][2048]
    unsigned short* ao = xn;                                 // reuse after QKV GEMM

    prep_k<<<8192, 256, 0, stream>>>(x, gamma, w_qkv, w_out, xn, wtq, wto);
    gemm_bt_k<1, 128><<<dim3(24, 32), 256, 0, stream>>>(xn, wtq, nullptr, qw, kw, vw,
                                                        4096, 3072, 1024);
    attn_k<<<dim3(32, 32), 512, 0, stream>>>(qw, kw, vw, ao);
    gemm_bt_k<0, 64><<<dim3(8, 64), 256, 0, stream>>>(ao, wto, out, nullptr, nullptr,
                                                      nullptr, 4096, 1024, 1024);
}